// Round 2
// baseline (1156.271 us; speedup 1.0000x reference)
//
#include <hip/hip_runtime.h>
#include <stdint.h>

// BitNet attention: int8-exact BitLinear GEMMs (MFMA i8) + bf16 flash attention (MFMA bf16).
// fp32 inputs / fp32 output (reference dtypes). Internal q/k/v/P/V in bf16.
//  - GEMMs are TN (both operands K-contiguous rows), m97-style 128x128 tiles,
//    global_load_lds width=16, XOR chunk swizzle applied to the *global source*
//    address so LDS fragment reads are ~2-way bank aliased (free per m136).
//  - MFMA 16x16 C/D layout: col = lane&15, row = (lane>>4)*4 + reg.
//  - A/B frag (16x16x32 bf16): row = lane&15, 8 contiguous K elems at quad*8.
//  - A/B frag (16x16x64 i8):   row = lane&15, 16 contiguous K bytes at quad*16.

typedef float  f32x4 __attribute__((ext_vector_type(4)));
typedef short  s16x8 __attribute__((ext_vector_type(8)));
typedef int    i32x4 __attribute__((ext_vector_type(4)));

__device__ __forceinline__ uint16_t f2b(float f) {
  uint32_t u = __float_as_uint(f);
  return (uint16_t)((u + 0x7FFFu + ((u >> 16) & 1u)) >> 16);
}
__device__ __forceinline__ void gl_lds16(const void* g, void* l) {
  __builtin_amdgcn_global_load_lds((const __attribute__((address_space(1))) unsigned int*)g,
                                   (__attribute__((address_space(3))) unsigned int*)l, 16, 0, 0);
}
__device__ __forceinline__ f32x4 mfma_bf16(s16x8 a, s16x8 b, f32x4 c) {
  return __builtin_amdgcn_mfma_f32_16x16x32_bf16(a, b, c, 0, 0, 0);
}
__device__ __forceinline__ i32x4 mfma_i8(i32x4 a, i32x4 b, i32x4 c) {
  return __builtin_amdgcn_mfma_i32_16x16x64_i8(a, b, c, 0, 0, 0);
}

// ---------- per-row activation quant: absmax -> int8 (fp32 input) ----------
__global__ __launch_bounds__(256) void k_qact_f32(const float* __restrict__ x,
                                                  int8_t* __restrict__ xq, float* __restrict__ rs) {
  __shared__ float red[4];
  const int row = blockIdx.x, t = threadIdx.x;
  const float4* xr = (const float4*)(x + (size_t)row * 4096);
  float v[16];
  #pragma unroll
  for (int i = 0; i < 4; i++) {
    float4 f = xr[t + 256 * i];
    v[i*4+0] = f.x; v[i*4+1] = f.y; v[i*4+2] = f.z; v[i*4+3] = f.w;
  }
  float mx = 0.f;
  #pragma unroll
  for (int i = 0; i < 16; i++) mx = fmaxf(mx, fabsf(v[i]));
  for (int o = 1; o < 64; o <<= 1) mx = fmaxf(mx, __shfl_xor(mx, o));
  if ((t & 63) == 0) red[t >> 6] = mx;
  __syncthreads();
  mx = fmaxf(fmaxf(red[0], red[1]), fmaxf(red[2], red[3]));
  mx = fmaxf(mx, 1e-5f);
  const float a = 127.f / mx;
  if (t == 0) rs[row] = mx * (1.f / 127.f);
  uint32_t* dst = (uint32_t*)(xq + (size_t)row * 4096);
  #pragma unroll
  for (int i = 0; i < 4; i++) {
    uint32_t w = 0;
    #pragma unroll
    for (int j = 0; j < 4; j++) {
      float q = rintf(v[i*4+j] * a);
      q = fmaxf(-128.f, fminf(127.f, q));
      w |= ((uint32_t)((int)q & 255)) << (j * 8);
    }
    dst[t + 256 * i] = w;
  }
}

// ---------- weight abs-sum (double accumulation, for mean) ----------
__global__ __launch_bounds__(256) void k_abssum(const float* __restrict__ w, double* __restrict__ outp) {
  __shared__ double red[4];
  const int t = threadIdx.x;
  size_t i0 = ((size_t)blockIdx.x * 256 + t) * 8;
  float4 u0 = *(const float4*)(w + i0);
  float4 u1 = *(const float4*)(w + i0 + 4);
  double s = (double)fabsf(u0.x) + (double)fabsf(u0.y) + (double)fabsf(u0.z) + (double)fabsf(u0.w)
           + (double)fabsf(u1.x) + (double)fabsf(u1.y) + (double)fabsf(u1.z) + (double)fabsf(u1.w);
  for (int o = 1; o < 64; o <<= 1) s += __shfl_xor(s, o);
  if ((t & 63) == 0) red[t >> 6] = s;
  __syncthreads();
  if (t == 0) atomicAdd(outp, red[0] + red[1] + red[2] + red[3]);
}

// ---------- weight ternary quant ----------
__global__ __launch_bounds__(256) void k_quant_w(const float* __restrict__ w, int8_t* __restrict__ wq,
                                                 const double* __restrict__ sum, double inv_n) {
  const float ws = (float)fmax(sum[0] * inv_n, 1e-5);
  size_t i0 = ((size_t)blockIdx.x * 256 + threadIdx.x) * 8;
  float4 u0 = *(const float4*)(w + i0);
  float4 u1 = *(const float4*)(w + i0 + 4);
  float hv[8] = {u0.x, u0.y, u0.z, u0.w, u1.x, u1.y, u1.z, u1.w};
  uint32_t lo = 0, hi = 0;
  #pragma unroll
  for (int j = 0; j < 8; j++) {
    float q = rintf(hv[j] / ws);
    q = fmaxf(-1.f, fminf(1.f, q));
    uint32_t b = (uint32_t)((int)q & 255);
    if (j < 4) lo |= b << (j * 8); else hi |= b << ((j - 4) * 8);
  }
  *(uint2*)(wq + i0) = make_uint2(lo, hi);
}

// ---------- int8 GEMM (TN): C[m][n] = sum_k A[m][k]*Bw[n][k] ----------
// MODE 0: QKV (N=6144), scatter to bf16 q/k/v buffers.  MODE 1: O-proj (N=4096) -> fp32 out.
template<int MODE>
__global__ __launch_bounds__(256) void k_gemm_i8(const int8_t* __restrict__ A, const int8_t* __restrict__ Bw,
                                                 const float* __restrict__ rs, const double* __restrict__ sums,
                                                 uint16_t* __restrict__ qb, uint16_t* __restrict__ kb,
                                                 uint16_t* __restrict__ vb, float* __restrict__ outp) {
  __shared__ int8_t lA[16384];
  __shared__ int8_t lB[16384];
  const int bn = blockIdx.x, bm = blockIdx.y;
  const int t = threadIdx.x, wave = t >> 6, lane = t & 63;
  const int quad = lane >> 4, l15 = lane & 15;
  const int wm = wave >> 1, wn = wave & 1;

  i32x4 acc[4][4];
  #pragma unroll
  for (int i = 0; i < 4; i++)
    #pragma unroll
    for (int j = 0; j < 4; j++) acc[i][j] = (i32x4){0, 0, 0, 0};

  const size_t arow0 = (size_t)bm * 128;
  const size_t brow0 = (size_t)bn * 128;

  for (int k0 = 0; k0 < 4096; k0 += 128) {
    #pragma unroll
    for (int r = 0; r < 4; r++) {
      int off = r * 4096 + wave * 1024 + lane * 16;
      int row = off >> 7;
      int pos = (off >> 4) & 7;
      int chunk = pos ^ (row & 7);
      gl_lds16(A  + (arow0 + row) * 4096 + k0 + chunk * 16, lA + r * 4096 + wave * 1024);
      gl_lds16(Bw + (brow0 + row) * 4096 + k0 + chunk * 16, lB + r * 4096 + wave * 1024);
    }
    __syncthreads();
    #pragma unroll
    for (int ks = 0; ks < 2; ks++) {
      i32x4 af[4], bf[4];
      #pragma unroll
      for (int i = 0; i < 4; i++) {
        int m = wm * 64 + i * 16 + l15;
        int c = ks * 4 + quad;
        af[i] = *(const i32x4*)(lA + m * 128 + (c ^ (m & 7)) * 16);
        int n = wn * 64 + i * 16 + l15;
        bf[i] = *(const i32x4*)(lB + n * 128 + (c ^ (n & 7)) * 16);
      }
      #pragma unroll
      for (int i = 0; i < 4; i++)
        #pragma unroll
        for (int j = 0; j < 4; j++)
          acc[i][j] = mfma_i8(af[i], bf[j], acc[i][j]);
    }
    __syncthreads();
  }

  float wsc; int sel = 0;
  if (MODE == 0) {
    if (bn < 32)      { wsc = (float)fmax(sums[0] * (1.0 / 16777216.0), 1e-5); sel = 0; }
    else if (bn < 40) { wsc = (float)fmax(sums[1] * (1.0 / 4194304.0),  1e-5); sel = 1; }
    else              { wsc = (float)fmax(sums[2] * (1.0 / 4194304.0),  1e-5); sel = 2; }
  } else {
    wsc = (float)fmax(sums[3] * (1.0 / 16777216.0), 1e-5);
  }
  #pragma unroll
  for (int i = 0; i < 4; i++) {
    #pragma unroll
    for (int r = 0; r < 4; r++) {
      int token = bm * 128 + wm * 64 + i * 16 + quad * 4 + r;
      float rv = rs[token] * wsc;
      #pragma unroll
      for (int j = 0; j < 4; j++) {
        int o = bn * 128 + wn * 64 + j * 16 + l15;
        float val = (float)acc[i][j][r] * rv;
        if (MODE == 0) {
          int b = token >> 11, s2 = token & 2047;
          if (sel == 0) {
            int hh = o >> 7, d = o & 127;
            qb[(((size_t)b * 32 + hh) * 2048 + s2) * 128 + d] = f2b(val * 0.08838834764831845f);
          } else if (sel == 1) {
            int o2 = o - 4096; int g = o2 >> 7, d = o2 & 127;
            kb[(((size_t)b * 8 + g) * 2048 + s2) * 128 + d] = f2b(val);
          } else {
            int o2 = o - 5120; int g = o2 >> 7, d = o2 & 127;
            vb[(((size_t)b * 8 + g) * 2048 + s2) * 128 + d] = f2b(val);
          }
        } else {
          outp[(size_t)token * 4096 + o] = val;
        }
      }
    }
  }
}

// ---------- V transpose: [g][s][d] -> [g][d][s] (bf16) ----------
__global__ __launch_bounds__(256) void k_transpose_v(const uint16_t* __restrict__ v, uint16_t* __restrict__ vt) {
  __shared__ uint16_t tile[64][72];
  const int bs = blockIdx.x * 64, bd = blockIdx.y * 64, g = blockIdx.z;
  const int t = threadIdx.x;
  const uint16_t* src = v + ((size_t)g * 2048 + bs) * 128 + bd;
  #pragma unroll
  for (int it = 0; it < 2; it++) {
    int r = (t >> 3) + it * 32;
    int c = (t & 7) * 8;
    uint4 u = *(const uint4*)(src + (size_t)r * 128 + c);
    uint16_t* p = &tile[r][c];
    p[0] = u.x & 0xffff; p[1] = u.x >> 16; p[2] = u.y & 0xffff; p[3] = u.y >> 16;
    p[4] = u.z & 0xffff; p[5] = u.z >> 16; p[6] = u.w & 0xffff; p[7] = u.w >> 16;
  }
  __syncthreads();
  uint16_t* dst = vt + ((size_t)g * 128 + bd) * 2048 + bs;
  #pragma unroll
  for (int it = 0; it < 2; it++) {
    int r = (t >> 3) + it * 32;
    int c = (t & 7) * 8;
    uint32_t w0 = tile[c+0][r] | ((uint32_t)tile[c+1][r] << 16);
    uint32_t w1 = tile[c+2][r] | ((uint32_t)tile[c+3][r] << 16);
    uint32_t w2 = tile[c+4][r] | ((uint32_t)tile[c+5][r] << 16);
    uint32_t w3 = tile[c+6][r] | ((uint32_t)tile[c+7][r] << 16);
    *(uint4*)(dst + (size_t)r * 2048 + c) = make_uint4(w0, w1, w2, w3);
  }
}

// ---------- flash attention, base-2 online softmax (bf16 MFMA, fp32 out) ----------
__global__ __launch_bounds__(256) void k_attn(const uint16_t* __restrict__ qg, const uint16_t* __restrict__ kg,
                                              const uint16_t* __restrict__ vtg, float* __restrict__ attn) {
  __shared__ char smem[65536];   // [0,32K): K tile (then P overlay); [32K,64K): Vt tile (Q staging pre-loop)
  const int qt = blockIdx.x, bh = blockIdx.y;
  const int b = bh >> 5, h = bh & 31, kv = h >> 2;
  const int t = threadIdx.x, wave = t >> 6, lane = t & 63;
  const int quad = lane >> 4, l15 = lane & 15;

  const char* qsrc = (const char*)(qg + (((size_t)b * 32 + h) * 2048 + (size_t)qt * 128) * 128);
  const char* ksrc = (const char*)(kg + (((size_t)b * 8 + kv) * 2048) * 128);
  const char* vsrc = (const char*)(vtg + (((size_t)b * 8 + kv) * 128) * 2048);

  #pragma unroll
  for (int r = 0; r < 8; r++) {
    int off = r * 4096 + wave * 1024 + lane * 16;
    int row = off >> 8, pos = (off >> 4) & 15;
    int chunk = pos ^ (row & 7);
    gl_lds16(qsrc + (size_t)row * 256 + chunk * 16, smem + 32768 + r * 4096 + wave * 1024);
  }
  __syncthreads();
  s16x8 qf[2][4];
  #pragma unroll
  for (int mf = 0; mf < 2; mf++)
    #pragma unroll
    for (int ks = 0; ks < 4; ks++) {
      int m = wave * 32 + mf * 16 + l15;
      int c = ks * 4 + quad;
      qf[mf][ks] = *(const s16x8*)(smem + 32768 + m * 256 + (c ^ (m & 7)) * 16);
    }
  __syncthreads();

  float Mx[2][4], Ls[2][4];
  f32x4 Ov[2][8];
  #pragma unroll
  for (int mf = 0; mf < 2; mf++) {
    #pragma unroll
    for (int r = 0; r < 4; r++) { Mx[mf][r] = -3.0e38f; Ls[mf][r] = 0.f; }
    #pragma unroll
    for (int nf = 0; nf < 8; nf++) Ov[mf][nf] = (f32x4){0, 0, 0, 0};
  }

  for (int kt = 0; kt <= qt; kt++) {
    #pragma unroll
    for (int r = 0; r < 8; r++) {
      int off = r * 4096 + wave * 1024 + lane * 16;
      int row = off >> 8, pos = (off >> 4) & 15;
      int chunk = pos ^ (row & 7);
      gl_lds16(ksrc + ((size_t)(kt * 128 + row)) * 256 + chunk * 16, smem + r * 4096 + wave * 1024);
      gl_lds16(vsrc + (size_t)row * 4096 + (size_t)kt * 256 + chunk * 16,
               smem + 32768 + r * 4096 + wave * 1024);
    }
    __syncthreads();

    f32x4 sc[2][8];
    #pragma unroll
    for (int mf = 0; mf < 2; mf++)
      #pragma unroll
      for (int nf = 0; nf < 8; nf++) sc[mf][nf] = (f32x4){0, 0, 0, 0};

    #pragma unroll
    for (int ks = 0; ks < 4; ks++) {
      #pragma unroll
      for (int nf = 0; nf < 8; nf++) {
        int n = nf * 16 + l15;
        int c = ks * 4 + quad;
        s16x8 kf = *(const s16x8*)(smem + n * 256 + (c ^ (n & 7)) * 16);
        sc[0][nf] = mfma_bf16(qf[0][ks], kf, sc[0][nf]);
        sc[1][nf] = mfma_bf16(qf[1][ks], kf, sc[1][nf]);
      }
    }

    if (kt == qt) {
      #pragma unroll
      for (int mf = 0; mf < 2; mf++)
        #pragma unroll
        for (int nf = 0; nf < 8; nf++)
          #pragma unroll
          for (int r = 0; r < 4; r++) {
            int qrow = wave * 32 + mf * 16 + quad * 4 + r;
            int tcol = nf * 16 + l15;
            if (tcol > qrow) sc[mf][nf][r] = -3.0e38f;
          }
    }

    float mn[2][4], al[2][4];
    #pragma unroll
    for (int mf = 0; mf < 2; mf++)
      #pragma unroll
      for (int r = 0; r < 4; r++) {
        float x = sc[mf][0][r];
        #pragma unroll
        for (int nf = 1; nf < 8; nf++) x = fmaxf(x, sc[mf][nf][r]);
        x = fmaxf(x, __shfl_xor(x, 1));
        x = fmaxf(x, __shfl_xor(x, 2));
        x = fmaxf(x, __shfl_xor(x, 4));
        x = fmaxf(x, __shfl_xor(x, 8));
        float m2 = fmaxf(Mx[mf][r], x);
        al[mf][r] = exp2f(Mx[mf][r] - m2);
        Mx[mf][r] = m2;
        mn[mf][r] = m2;
      }

    __syncthreads();   // all waves done reading K before P overlays it

    float rsum[2][4] = {{0, 0, 0, 0}, {0, 0, 0, 0}};
    #pragma unroll
    for (int mf = 0; mf < 2; mf++)
      #pragma unroll
      for (int nf = 0; nf < 8; nf++)
        #pragma unroll
        for (int r = 0; r < 4; r++) {
          float pv = exp2f(sc[mf][nf][r] - mn[mf][r]);
          rsum[mf][r] += pv;
          int prow = wave * 32 + mf * 16 + quad * 4 + r;
          int pcol = nf * 16 + l15;
          int pos = (pcol >> 3) ^ (prow & 7);
          *(uint16_t*)(smem + prow * 256 + pos * 16 + (pcol & 7) * 2) = f2b(pv);
        }
    #pragma unroll
    for (int mf = 0; mf < 2; mf++)
      #pragma unroll
      for (int r = 0; r < 4; r++) {
        float s2 = rsum[mf][r];
        s2 += __shfl_xor(s2, 1); s2 += __shfl_xor(s2, 2);
        s2 += __shfl_xor(s2, 4); s2 += __shfl_xor(s2, 8);
        Ls[mf][r] = Ls[mf][r] * al[mf][r] + s2;
      }
    #pragma unroll
    for (int mf = 0; mf < 2; mf++)
      #pragma unroll
      for (int nf = 0; nf < 8; nf++)
        #pragma unroll
        for (int r = 0; r < 4; r++) Ov[mf][nf][r] *= al[mf][r];

    __syncthreads();   // P visible

    #pragma unroll
    for (int ks = 0; ks < 4; ks++) {
      s16x8 pf[2];
      #pragma unroll
      for (int mf = 0; mf < 2; mf++) {
        int m = wave * 32 + mf * 16 + l15;
        int c = ks * 4 + quad;
        pf[mf] = *(const s16x8*)(smem + m * 256 + (c ^ (m & 7)) * 16);
      }
      #pragma unroll
      for (int nf = 0; nf < 8; nf++) {
        int d = nf * 16 + l15;
        int c = ks * 4 + quad;
        s16x8 vf = *(const s16x8*)(smem + 32768 + d * 256 + (c ^ (d & 7)) * 16);
        Ov[0][nf] = mfma_bf16(pf[0], vf, Ov[0][nf]);
        Ov[1][nf] = mfma_bf16(pf[1], vf, Ov[1][nf]);
      }
    }
    __syncthreads();   // done with P/Vt before next staging
  }

  #pragma unroll
  for (int mf = 0; mf < 2; mf++)
    #pragma unroll
    for (int nf = 0; nf < 8; nf++)
      #pragma unroll
      for (int r = 0; r < 4; r++) {
        int qrow = qt * 128 + wave * 32 + mf * 16 + quad * 4 + r;
        size_t token = (size_t)b * 2048 + qrow;
        int d = nf * 16 + l15;
        attn[token * 4096 + (size_t)h * 128 + d] = Ov[mf][nf][r] / Ls[mf][r];
      }
}

extern "C" void kernel_launch(void* const* d_in, const int* in_sizes, int n_in,
                              void* d_out, int out_size, void* d_ws, size_t ws_size,
                              hipStream_t stream) {
  (void)in_sizes; (void)out_size;
  if (n_in < 6) return;
  const float* hs = (const float*)d_in[0];
  const float* Wq = (const float*)d_in[2];
  const float* Wk = (const float*)d_in[3];
  const float* Wv = (const float*)d_in[4];
  const float* Wo = (const float*)d_in[5];
  float* out = (float*)d_out;

  char* p = (char*)d_ws;
  size_t off = 0;
  auto take = [&](size_t bytes) { char* r = p + off; off += (bytes + 255) & ~(size_t)255; return r; };
  int8_t*   xq1  = (int8_t*)  take((size_t)4096 * 4096);
  float*    rs1  = (float*)   take(4096 * 4);
  int8_t*   wqkv = (int8_t*)  take((size_t)6144 * 4096);
  int8_t*   woq  = (int8_t*)  take((size_t)4096 * 4096);
  uint16_t* qb   = (uint16_t*)take((size_t)2 * 32 * 2048 * 128 * 2);
  uint16_t* kb   = (uint16_t*)take((size_t)2 * 8 * 2048 * 128 * 2);
  uint16_t* vb   = (uint16_t*)take((size_t)2 * 8 * 2048 * 128 * 2);
  uint16_t* vtb  = (uint16_t*)take((size_t)2 * 8 * 2048 * 128 * 2);
  float*    attn = (float*)   take((size_t)4096 * 4096 * 4);
  int8_t*   xq2  = (int8_t*)  take((size_t)4096 * 4096);
  float*    rs2  = (float*)   take(4096 * 4);
  double*   sums = (double*)  take(256);
  if (off > ws_size) return;

  (void)hipMemsetAsync(sums, 0, 32, stream);
  k_abssum<<<8192, 256, 0, stream>>>(Wq, sums + 0);
  k_abssum<<<2048, 256, 0, stream>>>(Wk, sums + 1);
  k_abssum<<<2048, 256, 0, stream>>>(Wv, sums + 2);
  k_abssum<<<8192, 256, 0, stream>>>(Wo, sums + 3);
  k_quant_w<<<8192, 256, 0, stream>>>(Wq, wqkv,                       sums + 0, 1.0 / 16777216.0);
  k_quant_w<<<2048, 256, 0, stream>>>(Wk, wqkv + (size_t)4096 * 4096, sums + 1, 1.0 / 4194304.0);
  k_quant_w<<<2048, 256, 0, stream>>>(Wv, wqkv + (size_t)5120 * 4096, sums + 2, 1.0 / 4194304.0);
  k_quant_w<<<8192, 256, 0, stream>>>(Wo, woq,                        sums + 3, 1.0 / 16777216.0);
  k_qact_f32<<<4096, 256, 0, stream>>>(hs, xq1, rs1);
  k_gemm_i8<0><<<dim3(48, 32), 256, 0, stream>>>(xq1, wqkv, rs1, sums, qb, kb, vb, (float*)nullptr);
  k_transpose_v<<<dim3(32, 2, 16), 256, 0, stream>>>(vb, vtb);
  k_attn<<<dim3(16, 64), 256, 0, stream>>>(qb, kb, vtb, attn);
  k_qact_f32<<<4096, 256, 0, stream>>>(attn, xq2, rs2);
  k_gemm_i8<1><<<dim3(32, 32), 256, 0, stream>>>(xq2, woq, rs2, sums,
                                                 (uint16_t*)nullptr, (uint16_t*)nullptr, (uint16_t*)nullptr, out);
}

// Round 3
// 885.620 us; speedup vs baseline: 1.3056x; 1.3056x over previous
//
#include <hip/hip_runtime.h>
#include <stdint.h>

// BitNet attention: int8-exact BitLinear GEMMs (MFMA i8) + bf16 flash attention (MFMA bf16).
// fp32 inputs / fp32 output (reference dtypes). Internal q/k/v/P in bf16.
//  - GEMMs are TN (both operands K-contiguous rows), m97-style 128x128 tiles,
//    global_load_lds width=16, XOR chunk swizzle applied to the *global source*
//    address so LDS fragment reads are ~2-way bank aliased (free per m136).
//  - MFMA 16x16 C/D layout: col(N) = lane&15, row(M) = (lane>>4)*4 + reg.
//  - A/B frag (16x16x32 bf16): operand row = lane&15, 8 contiguous K elems at quad*8.
//  - k_attn uses the transposed-score scheme: S^T = K·Q^T, O^T = Vt·P with P
//    moved C-layout -> B-layout via cross-quad shuffles (no LDS round trip).

typedef float  f32x4 __attribute__((ext_vector_type(4)));
typedef short  s16x8 __attribute__((ext_vector_type(8)));
typedef int    i32x4 __attribute__((ext_vector_type(4)));

__device__ __forceinline__ uint16_t f2b(float f) {
  uint32_t u = __float_as_uint(f);
  return (uint16_t)((u + 0x7FFFu + ((u >> 16) & 1u)) >> 16);
}
__device__ __forceinline__ void gl_lds16(const void* g, void* l) {
  __builtin_amdgcn_global_load_lds((const __attribute__((address_space(1))) unsigned int*)g,
                                   (__attribute__((address_space(3))) unsigned int*)l, 16, 0, 0);
}
__device__ __forceinline__ f32x4 mfma_bf16(s16x8 a, s16x8 b, f32x4 c) {
  return __builtin_amdgcn_mfma_f32_16x16x32_bf16(a, b, c, 0, 0, 0);
}
__device__ __forceinline__ i32x4 mfma_i8(i32x4 a, i32x4 b, i32x4 c) {
  return __builtin_amdgcn_mfma_i32_16x16x64_i8(a, b, c, 0, 0, 0);
}

// ---------- per-row activation quant: absmax -> int8 (fp32 input) ----------
__global__ __launch_bounds__(256) void k_qact_f32(const float* __restrict__ x,
                                                  int8_t* __restrict__ xq, float* __restrict__ rs) {
  __shared__ float red[4];
  const int row = blockIdx.x, t = threadIdx.x;
  const float4* xr = (const float4*)(x + (size_t)row * 4096);
  float v[16];
  #pragma unroll
  for (int i = 0; i < 4; i++) {
    float4 f = xr[t + 256 * i];
    v[i*4+0] = f.x; v[i*4+1] = f.y; v[i*4+2] = f.z; v[i*4+3] = f.w;
  }
  float mx = 0.f;
  #pragma unroll
  for (int i = 0; i < 16; i++) mx = fmaxf(mx, fabsf(v[i]));
  for (int o = 1; o < 64; o <<= 1) mx = fmaxf(mx, __shfl_xor(mx, o));
  if ((t & 63) == 0) red[t >> 6] = mx;
  __syncthreads();
  mx = fmaxf(fmaxf(red[0], red[1]), fmaxf(red[2], red[3]));
  mx = fmaxf(mx, 1e-5f);
  const float a = 127.f / mx;
  if (t == 0) rs[row] = mx * (1.f / 127.f);
  uint32_t* dst = (uint32_t*)(xq + (size_t)row * 4096);
  #pragma unroll
  for (int i = 0; i < 4; i++) {
    uint32_t w = 0;
    #pragma unroll
    for (int j = 0; j < 4; j++) {
      float q = rintf(v[i*4+j] * a);
      q = fmaxf(-128.f, fminf(127.f, q));
      w |= ((uint32_t)((int)q & 255)) << (j * 8);
    }
    dst[t + 256 * i] = w;
  }
}

// ---------- weight abs-sum (double accumulation, for mean) ----------
__global__ __launch_bounds__(256) void k_abssum(const float* __restrict__ w, double* __restrict__ outp) {
  __shared__ double red[4];
  const int t = threadIdx.x;
  size_t i0 = ((size_t)blockIdx.x * 256 + t) * 8;
  float4 u0 = *(const float4*)(w + i0);
  float4 u1 = *(const float4*)(w + i0 + 4);
  double s = (double)fabsf(u0.x) + (double)fabsf(u0.y) + (double)fabsf(u0.z) + (double)fabsf(u0.w)
           + (double)fabsf(u1.x) + (double)fabsf(u1.y) + (double)fabsf(u1.z) + (double)fabsf(u1.w);
  for (int o = 1; o < 64; o <<= 1) s += __shfl_xor(s, o);
  if ((t & 63) == 0) red[t >> 6] = s;
  __syncthreads();
  if (t == 0) atomicAdd(outp, red[0] + red[1] + red[2] + red[3]);
}

// ---------- weight ternary quant ----------
__global__ __launch_bounds__(256) void k_quant_w(const float* __restrict__ w, int8_t* __restrict__ wq,
                                                 const double* __restrict__ sum, double inv_n) {
  const float ws = (float)fmax(sum[0] * inv_n, 1e-5);
  size_t i0 = ((size_t)blockIdx.x * 256 + threadIdx.x) * 8;
  float4 u0 = *(const float4*)(w + i0);
  float4 u1 = *(const float4*)(w + i0 + 4);
  float hv[8] = {u0.x, u0.y, u0.z, u0.w, u1.x, u1.y, u1.z, u1.w};
  uint32_t lo = 0, hi = 0;
  #pragma unroll
  for (int j = 0; j < 8; j++) {
    float q = rintf(hv[j] / ws);
    q = fmaxf(-1.f, fminf(1.f, q));
    uint32_t b = (uint32_t)((int)q & 255);
    if (j < 4) lo |= b << (j * 8); else hi |= b << ((j - 4) * 8);
  }
  *(uint2*)(wq + i0) = make_uint2(lo, hi);
}

// ---------- int8 GEMM (TN): C[m][n] = sum_k A[m][k]*Bw[n][k] ----------
template<int MODE>
__global__ __launch_bounds__(256) void k_gemm_i8(const int8_t* __restrict__ A, const int8_t* __restrict__ Bw,
                                                 const float* __restrict__ rs, const double* __restrict__ sums,
                                                 uint16_t* __restrict__ qb, uint16_t* __restrict__ kb,
                                                 uint16_t* __restrict__ vb, float* __restrict__ outp) {
  __shared__ int8_t lA[16384];
  __shared__ int8_t lB[16384];
  const int bn = blockIdx.x, bm = blockIdx.y;
  const int t = threadIdx.x, wave = t >> 6, lane = t & 63;
  const int quad = lane >> 4, l15 = lane & 15;
  const int wm = wave >> 1, wn = wave & 1;

  i32x4 acc[4][4];
  #pragma unroll
  for (int i = 0; i < 4; i++)
    #pragma unroll
    for (int j = 0; j < 4; j++) acc[i][j] = (i32x4){0, 0, 0, 0};

  const size_t arow0 = (size_t)bm * 128;
  const size_t brow0 = (size_t)bn * 128;

  for (int k0 = 0; k0 < 4096; k0 += 128) {
    #pragma unroll
    for (int r = 0; r < 4; r++) {
      int off = r * 4096 + wave * 1024 + lane * 16;
      int row = off >> 7;
      int pos = (off >> 4) & 7;
      int chunk = pos ^ (row & 7);
      gl_lds16(A  + (arow0 + row) * 4096 + k0 + chunk * 16, lA + r * 4096 + wave * 1024);
      gl_lds16(Bw + (brow0 + row) * 4096 + k0 + chunk * 16, lB + r * 4096 + wave * 1024);
    }
    __syncthreads();
    #pragma unroll
    for (int ks = 0; ks < 2; ks++) {
      i32x4 af[4], bf[4];
      #pragma unroll
      for (int i = 0; i < 4; i++) {
        int m = wm * 64 + i * 16 + l15;
        int c = ks * 4 + quad;
        af[i] = *(const i32x4*)(lA + m * 128 + (c ^ (m & 7)) * 16);
        int n = wn * 64 + i * 16 + l15;
        bf[i] = *(const i32x4*)(lB + n * 128 + (c ^ (n & 7)) * 16);
      }
      #pragma unroll
      for (int i = 0; i < 4; i++)
        #pragma unroll
        for (int j = 0; j < 4; j++)
          acc[i][j] = mfma_i8(af[i], bf[j], acc[i][j]);
    }
    __syncthreads();
  }

  float wsc; int sel = 0;
  if (MODE == 0) {
    if (bn < 32)      { wsc = (float)fmax(sums[0] * (1.0 / 16777216.0), 1e-5); sel = 0; }
    else if (bn < 40) { wsc = (float)fmax(sums[1] * (1.0 / 4194304.0),  1e-5); sel = 1; }
    else              { wsc = (float)fmax(sums[2] * (1.0 / 4194304.0),  1e-5); sel = 2; }
  } else {
    wsc = (float)fmax(sums[3] * (1.0 / 16777216.0), 1e-5);
  }
  #pragma unroll
  for (int i = 0; i < 4; i++) {
    #pragma unroll
    for (int r = 0; r < 4; r++) {
      int token = bm * 128 + wm * 64 + i * 16 + quad * 4 + r;
      float rv = rs[token] * wsc;
      #pragma unroll
      for (int j = 0; j < 4; j++) {
        int o = bn * 128 + wn * 64 + j * 16 + l15;
        float val = (float)acc[i][j][r] * rv;
        if (MODE == 0) {
          int b = token >> 11, s2 = token & 2047;
          if (sel == 0) {
            int hh = o >> 7, d = o & 127;
            qb[(((size_t)b * 32 + hh) * 2048 + s2) * 128 + d] = f2b(val * 0.08838834764831845f);
          } else if (sel == 1) {
            int o2 = o - 4096; int g = o2 >> 7, d = o2 & 127;
            kb[(((size_t)b * 8 + g) * 2048 + s2) * 128 + d] = f2b(val);
          } else {
            int o2 = o - 5120; int g = o2 >> 7, d = o2 & 127;
            vb[(((size_t)b * 8 + g) * 2048 + s2) * 128 + d] = f2b(val);
          }
        } else {
          outp[(size_t)token * 4096 + o] = val;
        }
      }
    }
  }
}

// ---------- V transpose: [g][s][d] -> [g][d][s] (bf16) ----------
__global__ __launch_bounds__(256) void k_transpose_v(const uint16_t* __restrict__ v, uint16_t* __restrict__ vt) {
  __shared__ uint16_t tile[64][72];
  const int bs = blockIdx.x * 64, bd = blockIdx.y * 64, g = blockIdx.z;
  const int t = threadIdx.x;
  const uint16_t* src = v + ((size_t)g * 2048 + bs) * 128 + bd;
  #pragma unroll
  for (int it = 0; it < 2; it++) {
    int r = (t >> 3) + it * 32;
    int c = (t & 7) * 8;
    uint4 u = *(const uint4*)(src + (size_t)r * 128 + c);
    uint16_t* p = &tile[r][c];
    p[0] = u.x & 0xffff; p[1] = u.x >> 16; p[2] = u.y & 0xffff; p[3] = u.y >> 16;
    p[4] = u.z & 0xffff; p[5] = u.z >> 16; p[6] = u.w & 0xffff; p[7] = u.w >> 16;
  }
  __syncthreads();
  uint16_t* dst = vt + ((size_t)g * 128 + bd) * 2048 + bs;
  #pragma unroll
  for (int it = 0; it < 2; it++) {
    int r = (t >> 3) + it * 32;
    int c = (t & 7) * 8;
    uint32_t w0 = tile[c+0][r] | ((uint32_t)tile[c+1][r] << 16);
    uint32_t w1 = tile[c+2][r] | ((uint32_t)tile[c+3][r] << 16);
    uint32_t w2 = tile[c+4][r] | ((uint32_t)tile[c+5][r] << 16);
    uint32_t w3 = tile[c+6][r] | ((uint32_t)tile[c+7][r] << 16);
    *(uint4*)(dst + (size_t)r * 2048 + c) = make_uint4(w0, w1, w2, w3);
  }
}

// ---------- flash attention, transposed-score scheme ----------
// Grid: (8, 64). Block p handles Q-tiles qt=p and qt=15-p (17 kt-iterations total).
// S^T = K·Q^T  (A=K-frag m=key, B=Q-frag n=q)  -> C: col=q(lane&15), row=key(quad*4+r)
// O^T = Vt·P   (A=Vt-frag m=d,  B=P-frag  n=q) -> C: col=q,          row=d
// P goes C-layout -> B-layout in-register via cross-quad shuffles.
__global__ __launch_bounds__(256, 2) void k_attn(const uint16_t* __restrict__ qg, const uint16_t* __restrict__ kg,
                                                 const uint16_t* __restrict__ vtg, float* __restrict__ attn) {
  __shared__ char smem[65536];   // [0,32K): K tile; [32K,64K): Vt tile (Q staging pre-loop)
  const int p = blockIdx.x, bh = blockIdx.y;
  const int b = bh >> 5, h = bh & 31, kv = h >> 2;
  const int t = threadIdx.x, wave = t >> 6, lane = t & 63;
  const int quad = lane >> 4, l15 = lane & 15;

  const char* qbase = (const char*)(qg + (((size_t)b * 32 + h) * 2048) * 128);
  const char* ksrc  = (const char*)(kg + (((size_t)b * 8 + kv) * 2048) * 128);
  const char* vsrc  = (const char*)(vtg + (((size_t)b * 8 + kv) * 128) * 2048);

  for (int pass = 0; pass < 2; pass++) {
    const int qt = pass ? (15 - p) : p;

    __syncthreads();   // prior pass done with LDS
    #pragma unroll
    for (int r = 0; r < 8; r++) {
      int off = r * 4096 + wave * 1024 + lane * 16;
      int row = off >> 8, pos = (off >> 4) & 15;
      int chunk = pos ^ (row & 7);
      gl_lds16(qbase + (size_t)(qt * 128 + row) * 256 + chunk * 16, smem + 32768 + off);
    }
    __syncthreads();
    s16x8 qf[2][4];
    #pragma unroll
    for (int nf2 = 0; nf2 < 2; nf2++)
      #pragma unroll
      for (int ks = 0; ks < 4; ks++) {
        int n = wave * 32 + nf2 * 16 + l15;
        int c = ks * 4 + quad;
        qf[nf2][ks] = *(const s16x8*)(smem + 32768 + n * 256 + (c ^ (n & 7)) * 16);
      }

    float Mx[2] = {-3.0e38f, -3.0e38f};
    float Ls[2] = {0.f, 0.f};
    f32x4 Ov[8][2];
    #pragma unroll
    for (int mf = 0; mf < 8; mf++) { Ov[mf][0] = (f32x4){0,0,0,0}; Ov[mf][1] = (f32x4){0,0,0,0}; }

    for (int kt = 0; kt <= qt; kt++) {
      __syncthreads();   // qf read done / prev iter LDS reads done
      #pragma unroll
      for (int r = 0; r < 8; r++) {
        int off = r * 4096 + wave * 1024 + lane * 16;
        int row = off >> 8, pos = (off >> 4) & 15;
        int chunk = pos ^ (row & 7);
        gl_lds16(ksrc + (size_t)(kt * 128 + row) * 256 + chunk * 16, smem + off);
        gl_lds16(vsrc + (size_t)row * 4096 + (size_t)kt * 256 + chunk * 16, smem + 32768 + off);
      }
      __syncthreads();

      // ---- S^T = K·Q^T ----
      f32x4 sc[8][2];
      #pragma unroll
      for (int mf = 0; mf < 8; mf++) { sc[mf][0] = (f32x4){0,0,0,0}; sc[mf][1] = (f32x4){0,0,0,0}; }
      #pragma unroll
      for (int ks = 0; ks < 4; ks++) {
        #pragma unroll
        for (int mf = 0; mf < 8; mf++) {
          int m = mf * 16 + l15;
          int c = ks * 4 + quad;
          s16x8 kf = *(const s16x8*)(smem + m * 256 + (c ^ (m & 7)) * 16);
          sc[mf][0] = mfma_bf16(kf, qf[0][ks], sc[mf][0]);
          sc[mf][1] = mfma_bf16(kf, qf[1][ks], sc[mf][1]);
        }
      }

      if (kt == qt) {
        #pragma unroll
        for (int mf = 0; mf < 8; mf++)
          #pragma unroll
          for (int nf2 = 0; nf2 < 2; nf2++) {
            int qloc = wave * 32 + nf2 * 16 + l15;
            #pragma unroll
            for (int r = 0; r < 4; r++) {
              int kloc = mf * 16 + quad * 4 + r;
              if (kloc > qloc) sc[mf][nf2][r] = -3.0e38f;
            }
          }
      }

      // ---- online softmax over key dim (rows of S^T = regs + quads) ----
      float al[2];
      #pragma unroll
      for (int nf2 = 0; nf2 < 2; nf2++) {
        float x = sc[0][nf2][0];
        #pragma unroll
        for (int mf = 0; mf < 8; mf++)
          #pragma unroll
          for (int r = 0; r < 4; r++) x = fmaxf(x, sc[mf][nf2][r]);
        x = fmaxf(x, __shfl_xor(x, 16));
        x = fmaxf(x, __shfl_xor(x, 32));
        float m2 = fmaxf(Mx[nf2], x);
        al[nf2] = exp2f(Mx[nf2] - m2);
        Mx[nf2] = m2;
        float s = 0.f;
        #pragma unroll
        for (int mf = 0; mf < 8; mf++)
          #pragma unroll
          for (int r = 0; r < 4; r++) {
            float pv = exp2f(sc[mf][nf2][r] - m2);
            sc[mf][nf2][r] = pv;
            s += pv;
          }
        s += __shfl_xor(s, 16);
        s += __shfl_xor(s, 32);
        Ls[nf2] = Ls[nf2] * al[nf2] + s;
      }
      #pragma unroll
      for (int mf = 0; mf < 8; mf++)
        #pragma unroll
        for (int nf2 = 0; nf2 < 2; nf2++)
          #pragma unroll
          for (int r = 0; r < 4; r++) Ov[mf][nf2][r] *= al[nf2];

      // ---- O^T += Vt·P ----
      #pragma unroll
      for (int ks = 0; ks < 4; ks++) {
        // pack P for key blocks mf=2ks, 2ks+1: pk[mfp][nf2][pair]
        uint32_t pk[2][2][2];
        #pragma unroll
        for (int mfp = 0; mfp < 2; mfp++)
          #pragma unroll
          for (int nf2 = 0; nf2 < 2; nf2++)
            #pragma unroll
            for (int pr = 0; pr < 2; pr++)
              pk[mfp][nf2][pr] = (uint32_t)f2b(sc[2*ks+mfp][nf2][2*pr]) |
                                 ((uint32_t)f2b(sc[2*ks+mfp][nf2][2*pr+1]) << 16);
        // build B-fragments via cross-quad shuffles
        uint32_t pf[2][4];
        #pragma unroll
        for (int j2 = 0; j2 < 4; j2++) {
          int srcLane = ((quad & 1) * 2 + (j2 >> 1)) * 16 + l15;
          #pragma unroll
          for (int nf2 = 0; nf2 < 2; nf2++) {
            uint32_t a0 = __shfl(pk[0][nf2][j2 & 1], srcLane);
            uint32_t a1 = __shfl(pk[1][nf2][j2 & 1], srcLane);
            pf[nf2][j2] = (quad >= 2) ? a1 : a0;
          }
        }
        s16x8 pfr[2];
        pfr[0] = *(const s16x8*)&pf[0][0];
        pfr[1] = *(const s16x8*)&pf[1][0];
        #pragma unroll
        for (int mf = 0; mf < 8; mf++) {
          int m = mf * 16 + l15;
          int c = ks * 4 + quad;
          s16x8 vf = *(const s16x8*)(smem + 32768 + m * 256 + (c ^ (m & 7)) * 16);
          Ov[mf][0] = mfma_bf16(vf, pfr[0], Ov[mf][0]);
          Ov[mf][1] = mfma_bf16(vf, pfr[1], Ov[mf][1]);
        }
      }
    }

    // ---- write O^T (row=d, col=q) ----
    float inv[2] = {1.f / Ls[0], 1.f / Ls[1]};
    #pragma unroll
    for (int nf2 = 0; nf2 < 2; nf2++) {
      size_t token = (size_t)b * 2048 + qt * 128 + wave * 32 + nf2 * 16 + l15;
      float* obase = attn + token * 4096 + h * 128 + quad * 4;
      #pragma unroll
      for (int mf = 0; mf < 8; mf++) {
        float4 v4 = make_float4(Ov[mf][nf2][0] * inv[nf2], Ov[mf][nf2][1] * inv[nf2],
                                Ov[mf][nf2][2] * inv[nf2], Ov[mf][nf2][3] * inv[nf2]);
        *(float4*)(obase + mf * 16) = v4;
      }
    }
  }
}

extern "C" void kernel_launch(void* const* d_in, const int* in_sizes, int n_in,
                              void* d_out, int out_size, void* d_ws, size_t ws_size,
                              hipStream_t stream) {
  (void)in_sizes; (void)out_size;
  if (n_in < 6) return;
  const float* hs = (const float*)d_in[0];
  const float* Wq = (const float*)d_in[2];
  const float* Wk = (const float*)d_in[3];
  const float* Wv = (const float*)d_in[4];
  const float* Wo = (const float*)d_in[5];
  float* out = (float*)d_out;

  char* p = (char*)d_ws;
  size_t off = 0;
  auto take = [&](size_t bytes) { char* r = p + off; off += (bytes + 255) & ~(size_t)255; return r; };
  int8_t*   xq1  = (int8_t*)  take((size_t)4096 * 4096);
  float*    rs1  = (float*)   take(4096 * 4);
  int8_t*   wqkv = (int8_t*)  take((size_t)6144 * 4096);
  int8_t*   woq  = (int8_t*)  take((size_t)4096 * 4096);
  uint16_t* qb   = (uint16_t*)take((size_t)2 * 32 * 2048 * 128 * 2);
  uint16_t* kb   = (uint16_t*)take((size_t)2 * 8 * 2048 * 128 * 2);
  uint16_t* vb   = (uint16_t*)take((size_t)2 * 8 * 2048 * 128 * 2);
  uint16_t* vtb  = (uint16_t*)take((size_t)2 * 8 * 2048 * 128 * 2);
  float*    attn = (float*)   take((size_t)4096 * 4096 * 4);
  int8_t*   xq2  = (int8_t*)  take((size_t)4096 * 4096);
  float*    rs2  = (float*)   take(4096 * 4);
  double*   sums = (double*)  take(256);
  if (off > ws_size) return;

  (void)hipMemsetAsync(sums, 0, 32, stream);
  k_abssum<<<8192, 256, 0, stream>>>(Wq, sums + 0);
  k_abssum<<<2048, 256, 0, stream>>>(Wk, sums + 1);
  k_abssum<<<2048, 256, 0, stream>>>(Wv, sums + 2);
  k_abssum<<<8192, 256, 0, stream>>>(Wo, sums + 3);
  k_quant_w<<<8192, 256, 0, stream>>>(Wq, wqkv,                       sums + 0, 1.0 / 16777216.0);
  k_quant_w<<<2048, 256, 0, stream>>>(Wk, wqkv + (size_t)4096 * 4096, sums + 1, 1.0 / 4194304.0);
  k_quant_w<<<2048, 256, 0, stream>>>(Wv, wqkv + (size_t)5120 * 4096, sums + 2, 1.0 / 4194304.0);
  k_quant_w<<<8192, 256, 0, stream>>>(Wo, woq,                        sums + 3, 1.0 / 16777216.0);
  k_qact_f32<<<4096, 256, 0, stream>>>(hs, xq1, rs1);
  k_gemm_i8<0><<<dim3(48, 32), 256, 0, stream>>>(xq1, wqkv, rs1, sums, qb, kb, vb, (float*)nullptr);
  k_transpose_v<<<dim3(32, 2, 16), 256, 0, stream>>>(vb, vtb);
  k_attn<<<dim3(8, 64), 256, 0, stream>>>(qb, kb, vtb, attn);
  k_qact_f32<<<4096, 256, 0, stream>>>(attn, xq2, rs2);
  k_gemm_i8<1><<<dim3(32, 32), 256, 0, stream>>>(xq2, woq, rs2, sums,
                                                 (uint16_t*)nullptr, (uint16_t*)nullptr, (uint16_t*)nullptr, out);
}

// Round 4
// 679.517 us; speedup vs baseline: 1.7016x; 1.3033x over previous
//
#include <hip/hip_runtime.h>
#include <stdint.h>

// BitNet attention: int8-exact BitLinear GEMMs (MFMA i8) + bf16 flash attention (MFMA bf16).
// fp32 inputs / fp32 output. Internal q/k/v/P in bf16.
//  - GEMMs: TN, m97-style 128x128 tiles, global_load_lds width=16, XOR chunk swizzle
//    on the *global source* so LDS fragment reads are ~2-way bank aliased.
//  - MFMA 16x16 C/D layout: col(N)=lane&15, row(M)=(lane>>4)*4+reg.
//  - A/B frag (16x16x32 bf16): operand row = lane&15, 8 contiguous K elems at quad*8.
//  - k_attn: transposed-score scheme, Q-tile 64 / K-tile 64 (32 KB LDS -> 4 blocks/CU).
//    S^T = K·Q^T; O^T = Vt·P with P moved C-layout -> B-layout via cross-quad shuffles.

typedef float  f32x4 __attribute__((ext_vector_type(4)));
typedef short  s16x8 __attribute__((ext_vector_type(8)));
typedef int    i32x4 __attribute__((ext_vector_type(4)));

__device__ __forceinline__ uint16_t f2b(float f) {
  uint32_t u = __float_as_uint(f);
  return (uint16_t)((u + 0x7FFFu + ((u >> 16) & 1u)) >> 16);
}
__device__ __forceinline__ void gl_lds16(const void* g, void* l) {
  __builtin_amdgcn_global_load_lds((const __attribute__((address_space(1))) unsigned int*)g,
                                   (__attribute__((address_space(3))) unsigned int*)l, 16, 0, 0);
}
__device__ __forceinline__ f32x4 mfma_bf16(s16x8 a, s16x8 b, f32x4 c) {
  return __builtin_amdgcn_mfma_f32_16x16x32_bf16(a, b, c, 0, 0, 0);
}
__device__ __forceinline__ i32x4 mfma_i8(i32x4 a, i32x4 b, i32x4 c) {
  return __builtin_amdgcn_mfma_i32_16x16x64_i8(a, b, c, 0, 0, 0);
}

// ---------- per-row activation quant: absmax -> int8 (fp32 input) ----------
__global__ __launch_bounds__(256) void k_qact_f32(const float* __restrict__ x,
                                                  int8_t* __restrict__ xq, float* __restrict__ rs) {
  __shared__ float red[4];
  const int row = blockIdx.x, t = threadIdx.x;
  const float4* xr = (const float4*)(x + (size_t)row * 4096);
  float v[16];
  #pragma unroll
  for (int i = 0; i < 4; i++) {
    float4 f = xr[t + 256 * i];
    v[i*4+0] = f.x; v[i*4+1] = f.y; v[i*4+2] = f.z; v[i*4+3] = f.w;
  }
  float mx = 0.f;
  #pragma unroll
  for (int i = 0; i < 16; i++) mx = fmaxf(mx, fabsf(v[i]));
  for (int o = 1; o < 64; o <<= 1) mx = fmaxf(mx, __shfl_xor(mx, o));
  if ((t & 63) == 0) red[t >> 6] = mx;
  __syncthreads();
  mx = fmaxf(fmaxf(red[0], red[1]), fmaxf(red[2], red[3]));
  mx = fmaxf(mx, 1e-5f);
  const float a = 127.f / mx;
  if (t == 0) rs[row] = mx * (1.f / 127.f);
  uint32_t* dst = (uint32_t*)(xq + (size_t)row * 4096);
  #pragma unroll
  for (int i = 0; i < 4; i++) {
    uint32_t w = 0;
    #pragma unroll
    for (int j = 0; j < 4; j++) {
      float q = rintf(v[i*4+j] * a);
      q = fmaxf(-128.f, fminf(127.f, q));
      w |= ((uint32_t)((int)q & 255)) << (j * 8);
    }
    dst[t + 256 * i] = w;
  }
}

// ---------- fused weight abs-sum: block partials (no atomics) ----------
// Segments (blocks): Wq [0,1024), Wk [1024,1280), Wv [1280,1536), Wo [1536,2560).
// Each block covers 16384 floats.
__global__ __launch_bounds__(256) void k_abssum_part(const float* __restrict__ wq, const float* __restrict__ wk,
                                                     const float* __restrict__ wv, const float* __restrict__ wo,
                                                     double* __restrict__ part) {
  __shared__ double red[4];
  const int blk = blockIdx.x, t = threadIdx.x;
  const float* src; size_t base;
  if (blk < 1024)      { src = wq; base = (size_t)blk * 16384; }
  else if (blk < 1280) { src = wk; base = (size_t)(blk - 1024) * 16384; }
  else if (blk < 1536) { src = wv; base = (size_t)(blk - 1280) * 16384; }
  else                 { src = wo; base = (size_t)(blk - 1536) * 16384; }
  double s = 0.0;
  #pragma unroll
  for (int r = 0; r < 16; r++) {
    float4 f = *(const float4*)(src + base + r * 1024 + t * 4);
    s += (double)fabsf(f.x) + (double)fabsf(f.y) + (double)fabsf(f.z) + (double)fabsf(f.w);
  }
  for (int o = 1; o < 64; o <<= 1) s += __shfl_xor(s, o);
  if ((t & 63) == 0) red[t >> 6] = s;
  __syncthreads();
  if (t == 0) part[blk] = red[0] + red[1] + red[2] + red[3];
}

// ---------- reduce partials -> 4 sums (one block, wave w = segment w) ----------
__global__ __launch_bounds__(256) void k_reduce_sums(const double* __restrict__ part, double* __restrict__ sums) {
  const int w = threadIdx.x >> 6, lane = threadIdx.x & 63;
  const int s0 = (w == 0) ? 0 : (w == 1) ? 1024 : (w == 2) ? 1280 : 1536;
  const int s1 = (w == 0) ? 1024 : (w == 1) ? 1280 : (w == 2) ? 1536 : 2560;
  double s = 0.0;
  for (int i = s0 + lane; i < s1; i += 64) s += part[i];
  for (int o = 1; o < 64; o <<= 1) s += __shfl_xor(s, o);
  if (lane == 0) sums[w] = s;
}

// ---------- fused weight ternary quant (same segment map as abssum) ----------
__global__ __launch_bounds__(256) void k_quant_w_all(const float* __restrict__ wq, const float* __restrict__ wk,
                                                     const float* __restrict__ wv, const float* __restrict__ wo,
                                                     int8_t* __restrict__ wqkv, int8_t* __restrict__ woq,
                                                     const double* __restrict__ sums) {
  const int blk = blockIdx.x, t = threadIdx.x;
  const float* src; int8_t* dst; size_t base; int sidx; double ivn;
  if (blk < 1024)      { src = wq; dst = wqkv;                        base = (size_t)blk * 16384;          sidx = 0; ivn = 1.0 / 16777216.0; }
  else if (blk < 1280) { src = wk; dst = wqkv + (size_t)4096 * 4096;  base = (size_t)(blk - 1024) * 16384; sidx = 1; ivn = 1.0 / 4194304.0;  }
  else if (blk < 1536) { src = wv; dst = wqkv + (size_t)5120 * 4096;  base = (size_t)(blk - 1280) * 16384; sidx = 2; ivn = 1.0 / 4194304.0;  }
  else                 { src = wo; dst = woq;                         base = (size_t)(blk - 1536) * 16384; sidx = 3; ivn = 1.0 / 16777216.0; }
  const float ws = (float)fmax(sums[sidx] * ivn, 1e-5);
  #pragma unroll
  for (int r = 0; r < 16; r++) {
    size_t e = base + r * 1024 + t * 4;
    float4 f = *(const float4*)(src + e);
    float hv[4] = {f.x, f.y, f.z, f.w};
    uint32_t w = 0;
    #pragma unroll
    for (int j = 0; j < 4; j++) {
      float q = rintf(hv[j] / ws);
      q = fmaxf(-1.f, fminf(1.f, q));
      w |= ((uint32_t)((int)q & 255)) << (j * 8);
    }
    *(uint32_t*)(dst + e) = w;
  }
}

// ---------- int8 GEMM (TN): C[m][n] = sum_k A[m][k]*Bw[n][k] ----------
template<int MODE>
__global__ __launch_bounds__(256) void k_gemm_i8(const int8_t* __restrict__ A, const int8_t* __restrict__ Bw,
                                                 const float* __restrict__ rs, const double* __restrict__ sums,
                                                 uint16_t* __restrict__ qb, uint16_t* __restrict__ kb,
                                                 uint16_t* __restrict__ vb, float* __restrict__ outp) {
  __shared__ int8_t lA[16384];
  __shared__ int8_t lB[16384];
  const int bn = blockIdx.x, bm = blockIdx.y;
  const int t = threadIdx.x, wave = t >> 6, lane = t & 63;
  const int quad = lane >> 4, l15 = lane & 15;
  const int wm = wave >> 1, wn = wave & 1;

  i32x4 acc[4][4];
  #pragma unroll
  for (int i = 0; i < 4; i++)
    #pragma unroll
    for (int j = 0; j < 4; j++) acc[i][j] = (i32x4){0, 0, 0, 0};

  const size_t arow0 = (size_t)bm * 128;
  const size_t brow0 = (size_t)bn * 128;

  for (int k0 = 0; k0 < 4096; k0 += 128) {
    #pragma unroll
    for (int r = 0; r < 4; r++) {
      int off = r * 4096 + wave * 1024 + lane * 16;
      int row = off >> 7;
      int pos = (off >> 4) & 7;
      int chunk = pos ^ (row & 7);
      gl_lds16(A  + (arow0 + row) * 4096 + k0 + chunk * 16, lA + r * 4096 + wave * 1024);
      gl_lds16(Bw + (brow0 + row) * 4096 + k0 + chunk * 16, lB + r * 4096 + wave * 1024);
    }
    __syncthreads();
    #pragma unroll
    for (int ks = 0; ks < 2; ks++) {
      i32x4 af[4], bf[4];
      #pragma unroll
      for (int i = 0; i < 4; i++) {
        int m = wm * 64 + i * 16 + l15;
        int c = ks * 4 + quad;
        af[i] = *(const i32x4*)(lA + m * 128 + (c ^ (m & 7)) * 16);
        int n = wn * 64 + i * 16 + l15;
        bf[i] = *(const i32x4*)(lB + n * 128 + (c ^ (n & 7)) * 16);
      }
      #pragma unroll
      for (int i = 0; i < 4; i++)
        #pragma unroll
        for (int j = 0; j < 4; j++)
          acc[i][j] = mfma_i8(af[i], bf[j], acc[i][j]);
    }
    __syncthreads();
  }

  float wsc; int sel = 0;
  if (MODE == 0) {
    if (bn < 32)      { wsc = (float)fmax(sums[0] * (1.0 / 16777216.0), 1e-5); sel = 0; }
    else if (bn < 40) { wsc = (float)fmax(sums[1] * (1.0 / 4194304.0),  1e-5); sel = 1; }
    else              { wsc = (float)fmax(sums[2] * (1.0 / 4194304.0),  1e-5); sel = 2; }
  } else {
    wsc = (float)fmax(sums[3] * (1.0 / 16777216.0), 1e-5);
  }
  #pragma unroll
  for (int i = 0; i < 4; i++) {
    #pragma unroll
    for (int r = 0; r < 4; r++) {
      int token = bm * 128 + wm * 64 + i * 16 + quad * 4 + r;
      float rv = rs[token] * wsc;
      #pragma unroll
      for (int j = 0; j < 4; j++) {
        int o = bn * 128 + wn * 64 + j * 16 + l15;
        float val = (float)acc[i][j][r] * rv;
        if (MODE == 0) {
          int b = token >> 11, s2 = token & 2047;
          if (sel == 0) {
            int hh = o >> 7, d = o & 127;
            qb[(((size_t)b * 32 + hh) * 2048 + s2) * 128 + d] = f2b(val * 0.08838834764831845f);
          } else if (sel == 1) {
            int o2 = o - 4096; int g = o2 >> 7, d = o2 & 127;
            kb[(((size_t)b * 8 + g) * 2048 + s2) * 128 + d] = f2b(val);
          } else {
            int o2 = o - 5120; int g = o2 >> 7, d = o2 & 127;
            vb[(((size_t)b * 8 + g) * 2048 + s2) * 128 + d] = f2b(val);
          }
        } else {
          outp[(size_t)token * 4096 + o] = val;
        }
      }
    }
  }
}

// ---------- V transpose: [g][s][d] -> [g][d][s] (bf16) ----------
__global__ __launch_bounds__(256) void k_transpose_v(const uint16_t* __restrict__ v, uint16_t* __restrict__ vt) {
  __shared__ uint16_t tile[64][72];
  const int bs = blockIdx.x * 64, bd = blockIdx.y * 64, g = blockIdx.z;
  const int t = threadIdx.x;
  const uint16_t* src = v + ((size_t)g * 2048 + bs) * 128 + bd;
  #pragma unroll
  for (int it = 0; it < 2; it++) {
    int r = (t >> 3) + it * 32;
    int c = (t & 7) * 8;
    uint4 u = *(const uint4*)(src + (size_t)r * 128 + c);
    uint16_t* p = &tile[r][c];
    p[0] = u.x & 0xffff; p[1] = u.x >> 16; p[2] = u.y & 0xffff; p[3] = u.y >> 16;
    p[4] = u.z & 0xffff; p[5] = u.z >> 16; p[6] = u.w & 0xffff; p[7] = u.w >> 16;
  }
  __syncthreads();
  uint16_t* dst = vt + ((size_t)g * 128 + bd) * 2048 + bs;
  #pragma unroll
  for (int it = 0; it < 2; it++) {
    int r = (t >> 3) + it * 32;
    int c = (t & 7) * 8;
    uint32_t w0 = tile[c+0][r] | ((uint32_t)tile[c+1][r] << 16);
    uint32_t w1 = tile[c+2][r] | ((uint32_t)tile[c+3][r] << 16);
    uint32_t w2 = tile[c+4][r] | ((uint32_t)tile[c+5][r] << 16);
    uint32_t w3 = tile[c+6][r] | ((uint32_t)tile[c+7][r] << 16);
    *(uint4*)(dst + (size_t)r * 2048 + c) = make_uint4(w0, w1, w2, w3);
  }
}

// ---------- flash attention, transposed-score, Q=64 / K=64 tiles ----------
// Grid (16, 64). Block p handles Q-tiles qt=p and qt=31-p (33 kt-iterations total).
// LDS: [0,16K) K tile (Q staging pre-loop), [16K,32K) Vt tile. 4 blocks/CU.
__global__ __launch_bounds__(256, 4) void k_attn(const uint16_t* __restrict__ qg, const uint16_t* __restrict__ kg,
                                                 const uint16_t* __restrict__ vtg, float* __restrict__ attn) {
  __shared__ char smem[32768];
  const int p = blockIdx.x, bh = blockIdx.y;
  const int b = bh >> 5, h = bh & 31, kv = h >> 2;
  const int t = threadIdx.x, wave = t >> 6, lane = t & 63;
  const int quad = lane >> 4, l15 = lane & 15;

  const char* qbase = (const char*)(qg + (((size_t)b * 32 + h) * 2048) * 128);
  const char* ksrc  = (const char*)(kg + (((size_t)b * 8 + kv) * 2048) * 128);
  const char* vsrc  = (const char*)(vtg + (((size_t)b * 8 + kv) * 128) * 2048);

  for (int pass = 0; pass < 2; pass++) {
    const int qt = pass ? (31 - p) : p;

    __syncthreads();   // prior pass done with LDS
    // stage Q tile: 64 rows x 256 B into [0,16K)
    #pragma unroll
    for (int r = 0; r < 4; r++) {
      int off = r * 4096 + t * 16;
      int row = off >> 8, pos = (off >> 4) & 15;
      int chunk = pos ^ (row & 7);
      gl_lds16(qbase + (size_t)(qt * 64 + row) * 256 + chunk * 16, smem + off);
    }
    __syncthreads();
    s16x8 qf[4];
    #pragma unroll
    for (int ks = 0; ks < 4; ks++) {
      int n = wave * 16 + l15;           // this wave's q row
      int c = ks * 4 + quad;
      qf[ks] = *(const s16x8*)(smem + n * 256 + ((c ^ (n & 7))) * 16);
    }

    float Mx = -3.0e38f, Ls = 0.f;
    f32x4 Ov[8];
    #pragma unroll
    for (int mf = 0; mf < 8; mf++) Ov[mf] = (f32x4){0, 0, 0, 0};

    for (int kt = 0; kt <= qt; kt++) {
      __syncthreads();   // qf read done / prev iter LDS reads done
      #pragma unroll
      for (int r = 0; r < 4; r++) {
        int off = r * 4096 + t * 16;
        { int row = off >> 8, pos = (off >> 4) & 15, chunk = pos ^ (row & 7);
          gl_lds16(ksrc + (size_t)(kt * 64 + row) * 256 + chunk * 16, smem + off); }
        { int row = off >> 7, pos = (off >> 4) & 7, chunk = pos ^ (row & 7);
          gl_lds16(vsrc + (size_t)row * 4096 + kt * 128 + chunk * 16, smem + 16384 + off); }
      }
      __syncthreads();

      // ---- S^T = K·Q^T : C col=q(l15), row=key(quad*4+r) within mf block ----
      f32x4 sc[4];
      #pragma unroll
      for (int mf = 0; mf < 4; mf++) sc[mf] = (f32x4){0, 0, 0, 0};
      #pragma unroll
      for (int ks = 0; ks < 4; ks++) {
        #pragma unroll
        for (int mf = 0; mf < 4; mf++) {
          int m = mf * 16 + l15;
          int c = ks * 4 + quad;
          s16x8 kf = *(const s16x8*)(smem + m * 256 + ((c ^ (m & 7))) * 16);
          sc[mf] = mfma_bf16(kf, qf[ks], sc[mf]);
        }
      }

      if (kt == qt) {
        int qloc = wave * 16 + l15;
        #pragma unroll
        for (int mf = 0; mf < 4; mf++)
          #pragma unroll
          for (int r = 0; r < 4; r++) {
            int kloc = mf * 16 + quad * 4 + r;
            if (kloc > qloc) sc[mf][r] = -3.0e38f;
          }
      }

      // ---- online softmax over key dim (regs + cross-quad lanes) ----
      float x = sc[0][0];
      #pragma unroll
      for (int mf = 0; mf < 4; mf++)
        #pragma unroll
        for (int r = 0; r < 4; r++) x = fmaxf(x, sc[mf][r]);
      x = fmaxf(x, __shfl_xor(x, 16));
      x = fmaxf(x, __shfl_xor(x, 32));
      float m2 = fmaxf(Mx, x);
      float al = exp2f(Mx - m2);
      Mx = m2;
      float s = 0.f;
      #pragma unroll
      for (int mf = 0; mf < 4; mf++)
        #pragma unroll
        for (int r = 0; r < 4; r++) {
          float pv = exp2f(sc[mf][r] - m2);
          sc[mf][r] = pv;
          s += pv;
        }
      s += __shfl_xor(s, 16);
      s += __shfl_xor(s, 32);
      Ls = Ls * al + s;
      #pragma unroll
      for (int mf = 0; mf < 8; mf++)
        #pragma unroll
        for (int r = 0; r < 4; r++) Ov[mf][r] *= al;

      // ---- O^T += Vt·P : P C-layout -> B-layout via cross-quad shuffles ----
      #pragma unroll
      for (int ks = 0; ks < 2; ks++) {
        uint32_t pk[2][2];
        #pragma unroll
        for (int mfp = 0; mfp < 2; mfp++)
          #pragma unroll
          for (int pr = 0; pr < 2; pr++)
            pk[mfp][pr] = (uint32_t)f2b(sc[2*ks+mfp][2*pr]) |
                          ((uint32_t)f2b(sc[2*ks+mfp][2*pr+1]) << 16);
        uint32_t pf[4];
        #pragma unroll
        for (int j2 = 0; j2 < 4; j2++) {
          int srcLane = ((quad & 1) * 2 + (j2 >> 1)) * 16 + l15;
          uint32_t a0 = __shfl(pk[0][j2 & 1], srcLane);
          uint32_t a1 = __shfl(pk[1][j2 & 1], srcLane);
          pf[j2] = (quad >= 2) ? a1 : a0;
        }
        s16x8 pfr = *(const s16x8*)&pf[0];
        #pragma unroll
        for (int mf = 0; mf < 8; mf++) {
          int m = mf * 16 + l15;
          int c = ks * 4 + quad;
          s16x8 vf = *(const s16x8*)(smem + 16384 + m * 128 + ((c ^ (m & 7))) * 16);
          Ov[mf] = mfma_bf16(vf, pfr, Ov[mf]);
        }
      }
    }

    // ---- write O^T (row=d=quad*4+reg within mf, col=q=l15) ----
    float inv = 1.f / Ls;
    size_t token = (size_t)b * 2048 + qt * 64 + wave * 16 + l15;
    float* obase = attn + token * 4096 + h * 128 + quad * 4;
    #pragma unroll
    for (int mf = 0; mf < 8; mf++) {
      float4 v4 = make_float4(Ov[mf][0] * inv, Ov[mf][1] * inv, Ov[mf][2] * inv, Ov[mf][3] * inv);
      *(float4*)(obase + mf * 16) = v4;
    }
  }
}

extern "C" void kernel_launch(void* const* d_in, const int* in_sizes, int n_in,
                              void* d_out, int out_size, void* d_ws, size_t ws_size,
                              hipStream_t stream) {
  (void)in_sizes; (void)out_size;
  if (n_in < 6) return;
  const float* hs = (const float*)d_in[0];
  const float* Wq = (const float*)d_in[2];
  const float* Wk = (const float*)d_in[3];
  const float* Wv = (const float*)d_in[4];
  const float* Wo = (const float*)d_in[5];
  float* out = (float*)d_out;

  char* p = (char*)d_ws;
  size_t off = 0;
  auto take = [&](size_t bytes) { char* r = p + off; off += (bytes + 255) & ~(size_t)255; return r; };
  int8_t*   xq1  = (int8_t*)  take((size_t)4096 * 4096);
  float*    rs1  = (float*)   take(4096 * 4);
  int8_t*   wqkv = (int8_t*)  take((size_t)6144 * 4096);
  int8_t*   woq  = (int8_t*)  take((size_t)4096 * 4096);
  uint16_t* qb   = (uint16_t*)take((size_t)2 * 32 * 2048 * 128 * 2);
  uint16_t* kb   = (uint16_t*)take((size_t)2 * 8 * 2048 * 128 * 2);
  uint16_t* vb   = (uint16_t*)take((size_t)2 * 8 * 2048 * 128 * 2);
  uint16_t* vtb  = (uint16_t*)take((size_t)2 * 8 * 2048 * 128 * 2);
  float*    attn = (float*)   take((size_t)4096 * 4096 * 4);
  int8_t*   xq2  = (int8_t*)  take((size_t)4096 * 4096);
  float*    rs2  = (float*)   take(4096 * 4);
  double*   part = (double*)  take(2560 * 8);
  double*   sums = (double*)  take(256);
  if (off > ws_size) return;

  k_abssum_part<<<2560, 256, 0, stream>>>(Wq, Wk, Wv, Wo, part);
  k_reduce_sums<<<1, 256, 0, stream>>>(part, sums);
  k_quant_w_all<<<2560, 256, 0, stream>>>(Wq, Wk, Wv, Wo, wqkv, woq, sums);
  k_qact_f32<<<4096, 256, 0, stream>>>(hs, xq1, rs1);
  k_gemm_i8<0><<<dim3(48, 32), 256, 0, stream>>>(xq1, wqkv, rs1, sums, qb, kb, vb, (float*)nullptr);
  k_transpose_v<<<dim3(32, 2, 16), 256, 0, stream>>>(vb, vtb);
  k_attn<<<dim3(16, 64), 256, 0, stream>>>(qb, kb, vtb, attn);
  k_qact_f32<<<4096, 256, 0, stream>>>(attn, xq2, rs2);
  k_gemm_i8<1><<<dim3(32, 32), 256, 0, stream>>>(xq2, woq, rs2, sums,
                                                 (uint16_t*)nullptr, (uint16_t*)nullptr, (uint16_t*)nullptr, out);
}